// Round 2
// baseline (513.866 us; speedup 1.0000x reference)
//
#include <hip/hip_runtime.h>
#include <hip/hip_bf16.h>

#define IN_CH 512
#define OUT_CH 64
#define SCAN_CHUNK 2048   // 256 threads * 8 elements

typedef __attribute__((ext_vector_type(8))) short short8;
typedef __attribute__((ext_vector_type(4))) float f32x4;

static __device__ __forceinline__ unsigned short bf16bits(float f) {
    __hip_bfloat16 h = __float2bfloat16(f);
    return *reinterpret_cast<unsigned short*>(&h);
}
static __device__ __forceinline__ float bflo(unsigned int u) {  // low ushort as bf16 -> f32
    return __uint_as_float(u << 16);
}
static __device__ __forceinline__ float bfhi(unsigned int u) {  // high ushort as bf16 -> f32
    return __uint_as_float(u & 0xffff0000u);
}

// --- fused prep: zero cnt+cursor, W[512][64] -> Wt[64][512] bf16, zero sentinel row/dinv ---
__global__ void prep_kernel(const float* __restrict__ W, unsigned short* __restrict__ Wt,
                            unsigned int* __restrict__ cntcur, unsigned short* __restrict__ hs,
                            float* __restrict__ dinv, int N, int zb) {
    int b = blockIdx.x;
    if (b < zb) {
        unsigned int i = b * 256u + threadIdx.x;
        unsigned int tot4 = (unsigned int)N * 2u / 4u;
        if (i < tot4) {
            uint4 z = {0u, 0u, 0u, 0u};
            ((uint4*)cntcur)[i] = z;
        }
        return;
    }
    b -= zb;
    if (b < 128) {
        int i = b * 256 + threadIdx.x;   // 32768
        int k = i >> 6, n = i & 63;
        Wt[n * IN_CH + k] = bf16bits(W[i]);
        return;
    }
    if (threadIdx.x < OUT_CH) hs[(size_t)N * OUT_CH + threadIdx.x] = 0;
    if (threadIdx.x == 0) dinv[N] = 0.f;
}

// --- fused: MFMA GEMM (hs = x @ W, UNSCALED, bf16) + in-degree histogram ---
// GEMM K-loop restructured: 4 groups of 4 K-steps, group loads issued up-front,
// fully unrolled; __launch_bounds__(256,4) -> 128 VGPR cap so ~2 groups of x-loads
// stay in flight (was: 48 VGPR, one serialized memory round-trip per K-step).
__global__ void __launch_bounds__(256, 4) gemm_deg(const float* __restrict__ x,
                                                   const unsigned short* __restrict__ Wt,
                                                   unsigned short* __restrict__ hs, int N,
                                                   const int* __restrict__ col,
                                                   unsigned int* __restrict__ cnt, int E, int GB) {
    if ((int)blockIdx.x >= GB) {
        int i = ((int)blockIdx.x - GB) * 256 + threadIdx.x;
        int E4 = E >> 2;
        if (i < E4) {
            int4 c = ((const int4*)col)[i];
            atomicAdd(&cnt[c.x], 1u);
            atomicAdd(&cnt[c.y], 1u);
            atomicAdd(&cnt[c.z], 1u);
            atomicAdd(&cnt[c.w], 1u);
        } else if (i == E4) {
            for (int e = E4 * 4; e < E; ++e) atomicAdd(&cnt[col[e]], 1u);
        }
        return;
    }
    int wid = (int)((blockIdx.x * 256u + threadIdx.x) >> 6);
    int lane = threadIdx.x & 63;
    int row0 = wid * 16;
    if (row0 >= N) return;
    int m = lane & 15, q = lane >> 4;
    const float* xr = x + (size_t)(row0 + m) * IN_CH + q * 8;
    const unsigned short* wr = Wt + (size_t)m * IN_CH + q * 8;
    f32x4 acc[4];
#pragma unroll
    for (int t = 0; t < 4; ++t) acc[t] = (f32x4){0.f, 0.f, 0.f, 0.f};

#pragma unroll
    for (int g = 0; g < 4; ++g) {
        // issue all 8 x-loads for this group of 4 K-steps before any use
        f32x4 a[8];
#pragma unroll
        for (int u = 0; u < 4; ++u) {
            a[2 * u]     = *(const f32x4*)(xr + g * 128 + u * 32);
            a[2 * u + 1] = *(const f32x4*)(xr + g * 128 + u * 32 + 4);
        }
#pragma unroll
        for (int u = 0; u < 4; ++u) {
            short8 af;
            af[0] = (short)bf16bits(a[2 * u][0]);     af[1] = (short)bf16bits(a[2 * u][1]);
            af[2] = (short)bf16bits(a[2 * u][2]);     af[3] = (short)bf16bits(a[2 * u][3]);
            af[4] = (short)bf16bits(a[2 * u + 1][0]); af[5] = (short)bf16bits(a[2 * u + 1][1]);
            af[6] = (short)bf16bits(a[2 * u + 1][2]); af[7] = (short)bf16bits(a[2 * u + 1][3]);
#pragma unroll
            for (int t = 0; t < 4; ++t) {
                short8 bf = *(const short8*)(wr + (size_t)t * 16 * IN_CH + g * 128 + u * 32);
                acc[t] = __builtin_amdgcn_mfma_f32_16x16x32_bf16(af, bf, acc[t], 0, 0, 0);
            }
        }
    }
    // C/D layout: col = lane&15, row (within 16) = q*4 + reg
#pragma unroll
    for (int r = 0; r < 4; ++r) {
#pragma unroll
        for (int t = 0; t < 4; ++t)
            hs[(size_t)(row0 + q * 4 + r) * OUT_CH + t * 16 + m] = bf16bits(acc[t][r]);
    }
}

// --- scan A: per-chunk exclusive scan of counts padded to mult of 4 (uint4 alignment); also dinv ---
__global__ void scan_a(const unsigned int* __restrict__ cnt, float* __restrict__ dinv,
                       unsigned int* __restrict__ rowptr, unsigned int* __restrict__ blockSums, int N) {
    __shared__ unsigned int wsum[4];
    int t = threadIdx.x, b = blockIdx.x;
    int base = b * SCAN_CHUNK + t * 8;
    unsigned int p[8];
    unsigned int run = 0;
#pragma unroll
    for (int j = 0; j < 8; ++j) {
        unsigned int v = (base + j < N) ? cnt[base + j] : 0u;
        if (base + j < N) dinv[base + j] = rsqrtf((float)(v + 1u));
        p[j] = run;
        run += (v + 3u) & ~3u;   // pad to mult of 4 -> segment starts uint4-aligned
    }
    unsigned int s = run;
    unsigned int si = s;
#pragma unroll
    for (int off = 1; off < 64; off <<= 1) {
        unsigned int o = __shfl_up(si, off, 64);
        if ((t & 63) >= off) si += o;
    }
    if ((t & 63) == 63) wsum[t >> 6] = si;
    __syncthreads();
    unsigned int woff = 0;
    int w = t >> 6;
    for (int k = 0; k < w; ++k) woff += wsum[k];
    unsigned int exc = woff + si - s;
#pragma unroll
    for (int j = 0; j < 8; ++j)
        if (base + j < N) rowptr[base + j] = exc + p[j];
    if (t == 255) blockSums[b] = woff + si;
}

// --- scan B: exclusive scan of block totals (single wave, nb<=64) ---
__global__ void scan_b(const unsigned int* __restrict__ blockSums, unsigned int* __restrict__ blockOff, int nb) {
    int t = threadIdx.x;
    unsigned int s = (t < nb) ? blockSums[t] : 0u;
    unsigned int si = s;
#pragma unroll
    for (int off = 1; off < 64; off <<= 1) {
        unsigned int o = __shfl_up(si, off, 64);
        if (t >= off) si += o;
    }
    blockOff[t] = si - s;
}

// --- fill CSR: srcIdx[segment(col)] = row, 4 edges/thread. No init needed: gather clamps tails. ---
__global__ void fill_kernel(const int* __restrict__ ei, const unsigned int* __restrict__ rowptr,
                            const unsigned int* __restrict__ blockOff, unsigned int* __restrict__ cursor,
                            unsigned int* __restrict__ srcIdx, int E) {
    int E4 = E >> 2;
    int i = blockIdx.x * 256 + threadIdx.x;
    if (i < E4) {
        int4 r = ((const int4*)ei)[i];
        int4 c = ((const int4*)(ei + E))[i];
        unsigned int pos;
        pos = rowptr[c.x] + blockOff[c.x >> 11] + atomicAdd(&cursor[c.x], 1u); srcIdx[pos] = (unsigned int)r.x;
        pos = rowptr[c.y] + blockOff[c.y >> 11] + atomicAdd(&cursor[c.y], 1u); srcIdx[pos] = (unsigned int)r.y;
        pos = rowptr[c.z] + blockOff[c.z >> 11] + atomicAdd(&cursor[c.z], 1u); srcIdx[pos] = (unsigned int)r.z;
        pos = rowptr[c.w] + blockOff[c.w >> 11] + atomicAdd(&cursor[c.w], 1u); srcIdx[pos] = (unsigned int)r.w;
    } else if (i == E4) {
        for (int e = E4 * 4; e < E; ++e) {
            int r = ei[e], c = ei[E + e];
            unsigned int pos = rowptr[c] + blockOff[c >> 11] + atomicAdd(&cursor[c], 1u);
            srcIdx[pos] = (unsigned int)r;
        }
    }
}

// --- fused gather + self + bias + log_softmax. One wave/node; half-waves cover 4 edges each.
//     hs is UNSCALED: each message multiplied by dinv[src]; tail slots clamped to sentinel N
//     (dinv[N]=0, hs[N]=0) so srcIdx needs no initialization. ---
__global__ void __launch_bounds__(256) gather_kernel(const unsigned int* __restrict__ srcIdx,
                                                     const unsigned int* __restrict__ rowptr,
                                                     const unsigned int* __restrict__ blockOff,
                                                     const unsigned int* __restrict__ cnt,
                                                     const float* __restrict__ dinv,
                                                     const unsigned short* __restrict__ hs,
                                                     const float* __restrict__ bias,
                                                     float* __restrict__ out, int N) {
    int node = (int)((blockIdx.x * (unsigned long long)blockDim.x + threadIdx.x) >> 6);
    int lane = threadIdx.x & 63;
    if (node >= N) return;
    int sub = lane >> 5, ch2 = lane & 31;   // lane covers channels 2*ch2, 2*ch2+1
    unsigned int start = rowptr[node] + blockOff[node >> 11];
    unsigned int cn = cnt[node];
    unsigned int iters = (cn + 7u) >> 3;   // 8 edges per iter (4 per half-wave)
    const uint4* sp = (const uint4*)(srcIdx + start + sub * 4);
    unsigned int sent = (unsigned int)N;
    float acc0 = 0.f, acc1 = 0.f;
    for (unsigned int it = 0; it < iters; ++it) {
        uint4 iv = sp[it * 2];
        unsigned int slot = it * 8u + (unsigned int)sub * 4u;
        unsigned int i0 = (slot + 0u < cn) ? iv.x : sent;
        unsigned int i1 = (slot + 1u < cn) ? iv.y : sent;
        unsigned int i2 = (slot + 2u < cn) ? iv.z : sent;
        unsigned int i3 = (slot + 3u < cn) ? iv.w : sent;
        float d0 = dinv[i0], d1 = dinv[i1], d2 = dinv[i2], d3 = dinv[i3];
        unsigned int u0 = *(const unsigned int*)(hs + (size_t)i0 * OUT_CH + 2 * ch2);
        unsigned int u1 = *(const unsigned int*)(hs + (size_t)i1 * OUT_CH + 2 * ch2);
        unsigned int u2 = *(const unsigned int*)(hs + (size_t)i2 * OUT_CH + 2 * ch2);
        unsigned int u3 = *(const unsigned int*)(hs + (size_t)i3 * OUT_CH + 2 * ch2);
        acc0 += bflo(u0) * d0 + bflo(u1) * d1 + bflo(u2) * d2 + bflo(u3) * d3;
        acc1 += bfhi(u0) * d0 + bfhi(u1) * d1 + bfhi(u2) * d2 + bfhi(u3) * d3;
    }
    acc0 += __shfl_xor(acc0, 32, 64);
    acc1 += __shfl_xor(acc1, 32, 64);
    // self-loop term: + hs[node]*dinv[node]; whole thing scaled by dinv[node]
    float di = dinv[node];
    unsigned int us = *(const unsigned int*)(hs + (size_t)node * OUT_CH + 2 * ch2);
    acc0 = fmaf(bflo(us), di, acc0);
    acc1 = fmaf(bfhi(us), di, acc1);
    float2 bb = *(const float2*)(bias + 2 * ch2);
    float v0 = fmaf(acc0, di, bb.x);
    float v1 = fmaf(acc1, di, bb.y);
    // log_softmax over 64 channels; each half-wave holds all channels (2/lane over 32 lanes)
    float mx = fmaxf(v0, v1);
#pragma unroll
    for (int off = 16; off > 0; off >>= 1) mx = fmaxf(mx, __shfl_xor(mx, off, 64));
    float s = expf(v0 - mx) + expf(v1 - mx);
#pragma unroll
    for (int off = 16; off > 0; off >>= 1) s += __shfl_xor(s, off, 64);
    float ls = logf(s);
    if (sub == 0) {
        float2 o = {v0 - mx - ls, v1 - mx - ls};
        *(float2*)(out + (size_t)node * OUT_CH + 2 * ch2) = o;
    }
}

extern "C" void kernel_launch(void* const* d_in, const int* in_sizes, int n_in,
                              void* d_out, int out_size, void* d_ws, size_t ws_size,
                              hipStream_t stream) {
    const float* x  = (const float*)d_in[0];
    const int*   ei = (const int*)d_in[1];
    const float* W  = (const float*)d_in[2];
    const float* b  = (const float*)d_in[3];
    float* out = (float*)d_out;

    const int N = in_sizes[0] / IN_CH;   // 100000
    const int E = in_sizes[1] / 2;       // 1600000
    const int NBLK = (N + SCAN_CHUNK - 1) / SCAN_CHUNK;  // 49

    char* ws = (char*)d_ws;
    size_t o = 0;
    // cnt and cursor MUST stay adjacent (zeroed together in prep_kernel)
    unsigned int* cnt      = (unsigned int*)(ws + o); o += (size_t)N * 4;
    unsigned int* cursor   = (unsigned int*)(ws + o); o += (size_t)N * 4;
    unsigned int* rowptr   = (unsigned int*)(ws + o); o += (size_t)N * 4;
    unsigned int* blockSums= (unsigned int*)(ws + o); o += 256;
    unsigned int* blockOff = (unsigned int*)(ws + o); o += 256;
    float*        dinv     = (float*)(ws + o);        o += ((size_t)(N + 1) * 4 + 15) & ~15ull;
    unsigned int* srcIdx   = (unsigned int*)(ws + o); o += ((size_t)E + 3u * (size_t)N + 64) * 4;
    unsigned short* Wt     = (unsigned short*)(ws + o); o += (size_t)IN_CH * OUT_CH * 2;
    unsigned short* hs     = (unsigned short*)(ws + o); o += (size_t)(N + 1) * OUT_CH * 2;

    const int zb = (N * 2 / 4 + 255) / 256;       // uint4 blocks to zero cnt+cursor (196)
    const int GB = (N + 63) / 64;                 // gemm blocks (4 waves * 16 rows) = 1563
    const int DB = (E / 4 + 1 + 255) / 256;       // deg/fill blocks = 1563

    prep_kernel<<<zb + 129, 256, 0, stream>>>(W, Wt, cnt, hs, dinv, N, zb);
    gemm_deg<<<GB + DB, 256, 0, stream>>>(x, Wt, hs, N, ei + E, cnt, E, GB);
    scan_a<<<NBLK, 256, 0, stream>>>(cnt, dinv, rowptr, blockSums, N);
    scan_b<<<1, 64, 0, stream>>>(blockSums, blockOff, NBLK);
    fill_kernel<<<DB, 256, 0, stream>>>(ei, rowptr, blockOff, cursor, srcIdx, E);
    gather_kernel<<<((size_t)N * 64 + 255) / 256, 256, 0, stream>>>(srcIdx, rowptr, blockOff, cnt, dinv, hs, b, out, N);
}

// Round 3
// 506.864 us; speedup vs baseline: 1.0138x; 1.0138x over previous
//
#include <hip/hip_runtime.h>
#include <hip/hip_bf16.h>

#define IN_CH 512
#define OUT_CH 64
#define SCAN_CHUNK 2048   // 256 threads * 8 elements
#define G_PART 256        // edge partitions (one block each in histo/fill)
#define NW_MAX 25088      // LDS words: ceil(N/4), N<=100352

typedef __attribute__((ext_vector_type(8))) short short8;
typedef __attribute__((ext_vector_type(4))) float f32x4;

static __device__ __forceinline__ unsigned short bf16bits(float f) {
    __hip_bfloat16 h = __float2bfloat16(f);
    return *reinterpret_cast<unsigned short*>(&h);
}
static __device__ __forceinline__ float bflo(unsigned int u) {  // low ushort as bf16 -> f32
    return __uint_as_float(u << 16);
}
static __device__ __forceinline__ float bfhi(unsigned int u) {  // high ushort as bf16 -> f32
    return __uint_as_float(u & 0xffff0000u);
}

// --- prep: W[512][64] -> Wt[64][512] bf16; sentinel hs row N + dinv[N]=0 ---
// (no cnt/cursor zeroing anymore: cnt is fully written by reduce_kernel, cursor is gone)
__global__ void prep_kernel(const float* __restrict__ W, unsigned short* __restrict__ Wt,
                            unsigned short* __restrict__ hs, float* __restrict__ dinv, int N) {
    int b = blockIdx.x;
    if (b < 128) {
        int i = b * 256 + threadIdx.x;   // 32768
        int k = i >> 6, n = i & 63;
        Wt[n * IN_CH + k] = bf16bits(W[i]);
        return;
    }
    if (threadIdx.x < OUT_CH) hs[(size_t)N * OUT_CH + threadIdx.x] = 0;
    if (threadIdx.x == 0) dinv[N] = 0.f;
}

// --- MFMA GEMM: hs = x @ W (UNSCALED), bf16. One wave per 16 rows. ---
__global__ void __launch_bounds__(256, 4) gemm_kernel(const float* __restrict__ x,
                                                      const unsigned short* __restrict__ Wt,
                                                      unsigned short* __restrict__ hs, int N) {
    int wid = (int)((blockIdx.x * 256u + threadIdx.x) >> 6);
    int lane = threadIdx.x & 63;
    int row0 = wid * 16;
    if (row0 >= N) return;
    int m = lane & 15, q = lane >> 4;
    const float* xr = x + (size_t)(row0 + m) * IN_CH + q * 8;
    const unsigned short* wr = Wt + (size_t)m * IN_CH + q * 8;
    f32x4 acc[4];
#pragma unroll
    for (int t = 0; t < 4; ++t) acc[t] = (f32x4){0.f, 0.f, 0.f, 0.f};

#pragma unroll
    for (int g = 0; g < 4; ++g) {
        f32x4 a[8];
#pragma unroll
        for (int u = 0; u < 4; ++u) {
            a[2 * u]     = *(const f32x4*)(xr + g * 128 + u * 32);
            a[2 * u + 1] = *(const f32x4*)(xr + g * 128 + u * 32 + 4);
        }
#pragma unroll
        for (int u = 0; u < 4; ++u) {
            short8 af;
            af[0] = (short)bf16bits(a[2 * u][0]);     af[1] = (short)bf16bits(a[2 * u][1]);
            af[2] = (short)bf16bits(a[2 * u][2]);     af[3] = (short)bf16bits(a[2 * u][3]);
            af[4] = (short)bf16bits(a[2 * u + 1][0]); af[5] = (short)bf16bits(a[2 * u + 1][1]);
            af[6] = (short)bf16bits(a[2 * u + 1][2]); af[7] = (short)bf16bits(a[2 * u + 1][3]);
#pragma unroll
            for (int t = 0; t < 4; ++t) {
                short8 bf = *(const short8*)(wr + (size_t)t * 16 * IN_CH + g * 128 + u * 32);
                acc[t] = __builtin_amdgcn_mfma_f32_16x16x32_bf16(af, bf, acc[t], 0, 0, 0);
            }
        }
    }
    // C/D layout: col = lane&15, row (within 16) = q*4 + reg
#pragma unroll
    for (int r = 0; r < 4; ++r) {
#pragma unroll
        for (int t = 0; t < 4; ++t)
            hs[(size_t)(row0 + q * 4 + r) * OUT_CH + t * 16 + m] = bf16bits(acc[t][r]);
    }
}

// --- histo: per-partition LDS 8-bit histogram (4 nodes/word), flushed with plain stores.
//     NO global atomics. Per-(partition,node) count < 256 -> packed bytes never carry. ---
__global__ void __launch_bounds__(256) histo_kernel(const int* __restrict__ col,
                                                    unsigned int* __restrict__ hist8,
                                                    int N, int E) {
    __shared__ unsigned int h[NW_MAX];
    int NW = (N + 3) >> 2;
    int g = blockIdx.x;
    for (int w = threadIdx.x; w < NW; w += 256) h[w] = 0u;
    __syncthreads();
    int P = (E + G_PART - 1) / G_PART;
    int e0 = g * P, e1 = min(e0 + P, E);
    for (int e = e0 + (int)threadIdx.x; e < e1; e += 256) {
        int c = col[e];
        atomicAdd(&h[c >> 2], 1u << ((c & 3) * 8));   // ds_add, no return
    }
    __syncthreads();
    unsigned int* dst = hist8 + (size_t)g * NW;
    for (int w = threadIdx.x; w < NW; w += 256) dst[w] = h[w];
}

// --- reduce: vertical packed prefix over the G_PART planes; emit exclusive prefix planes
//     pre8[g][w] and final counts cnt[node]. Packed u32 adds are carry-free (deg < 256). ---
__global__ void reduce_kernel(const unsigned int* __restrict__ hist8,
                              unsigned int* __restrict__ pre8,
                              unsigned int* __restrict__ cnt, int N) {
    int NW = (N + 3) >> 2;
    int w = blockIdx.x * 256 + threadIdx.x;
    if (w >= NW) return;
    unsigned int run = 0u;
    for (int g = 0; g < G_PART; ++g) {
        size_t idx = (size_t)g * NW + w;
        pre8[idx] = run;
        run += hist8[idx];
    }
    int n0 = w * 4;
#pragma unroll
    for (int j = 0; j < 4; ++j)
        if (n0 + j < N) cnt[n0 + j] = (run >> (j * 8)) & 0xffu;
}

// --- scan A: per-chunk exclusive scan of counts padded to mult of 4; also dinv ---
__global__ void scan_a(const unsigned int* __restrict__ cnt, float* __restrict__ dinv,
                       unsigned int* __restrict__ rowptr, unsigned int* __restrict__ blockSums, int N) {
    __shared__ unsigned int wsum[4];
    int t = threadIdx.x, b = blockIdx.x;
    int base = b * SCAN_CHUNK + t * 8;
    unsigned int p[8];
    unsigned int run = 0;
#pragma unroll
    for (int j = 0; j < 8; ++j) {
        unsigned int v = (base + j < N) ? cnt[base + j] : 0u;
        if (base + j < N) dinv[base + j] = rsqrtf((float)(v + 1u));
        p[j] = run;
        run += (v + 3u) & ~3u;   // pad to mult of 4 -> segment starts uint4-aligned
    }
    unsigned int s = run;
    unsigned int si = s;
#pragma unroll
    for (int off = 1; off < 64; off <<= 1) {
        unsigned int o = __shfl_up(si, off, 64);
        if ((t & 63) >= off) si += o;
    }
    if ((t & 63) == 63) wsum[t >> 6] = si;
    __syncthreads();
    unsigned int woff = 0;
    int w = t >> 6;
    for (int k = 0; k < w; ++k) woff += wsum[k];
    unsigned int exc = woff + si - s;
#pragma unroll
    for (int j = 0; j < 8; ++j)
        if (base + j < N) rowptr[base + j] = exc + p[j];
    if (t == 255) blockSums[b] = woff + si;
}

// --- scan B: exclusive scan of block totals (single wave, nb<=64) ---
__global__ void scan_b(const unsigned int* __restrict__ blockSums, unsigned int* __restrict__ blockOff, int nb) {
    int t = threadIdx.x;
    unsigned int s = (t < nb) ? blockSums[t] : 0u;
    unsigned int si = s;
#pragma unroll
    for (int off = 1; off < 64; off <<= 1) {
        unsigned int o = __shfl_up(si, off, 64);
        if (t >= off) si += o;
    }
    blockOff[t] = si - s;
}

// --- fill: same partitioning as histo; LDS packed-byte cursors (ds_add_rtn).
//     pos = rowptr[c] + blockOff + pre8[g][c] + localRank. NO global atomics. ---
__global__ void __launch_bounds__(256) fill_kernel(const int* __restrict__ ei,
                                                   const unsigned int* __restrict__ rowptr,
                                                   const unsigned int* __restrict__ blockOff,
                                                   const unsigned int* __restrict__ pre8,
                                                   unsigned int* __restrict__ srcIdx,
                                                   int N, int E) {
    __shared__ unsigned int cur[NW_MAX];
    int NW = (N + 3) >> 2;
    int g = blockIdx.x;
    for (int w = threadIdx.x; w < NW; w += 256) cur[w] = 0u;
    __syncthreads();
    const unsigned int* pre = pre8 + (size_t)g * NW;
    int P = (E + G_PART - 1) / G_PART;
    int e0 = g * P, e1 = min(e0 + P, E);
#pragma unroll 4
    for (int e = e0 + (int)threadIdx.x; e < e1; e += 256) {
        int r = ei[e];        // source
        int c = ei[E + e];    // target
        int sh = (c & 3) * 8;
        unsigned int old = atomicAdd(&cur[c >> 2], 1u << sh);
        unsigned int rank = (old >> sh) & 0xffu;
        unsigned int base = (pre[c >> 2] >> sh) & 0xffu;
        unsigned int pos = rowptr[c] + blockOff[c >> 11] + base + rank;
        srcIdx[pos] = (unsigned int)r;
    }
}

// --- fused gather + self + bias + log_softmax. One wave/node; half-waves cover 4 edges each.
//     hs is UNSCALED: each message multiplied by dinv[src]; tail slots clamped to sentinel N
//     (dinv[N]=0, hs[N]=0) so srcIdx padding needs no initialization. ---
__global__ void __launch_bounds__(256) gather_kernel(const unsigned int* __restrict__ srcIdx,
                                                     const unsigned int* __restrict__ rowptr,
                                                     const unsigned int* __restrict__ blockOff,
                                                     const unsigned int* __restrict__ cnt,
                                                     const float* __restrict__ dinv,
                                                     const unsigned short* __restrict__ hs,
                                                     const float* __restrict__ bias,
                                                     float* __restrict__ out, int N) {
    int node = (int)((blockIdx.x * (unsigned long long)blockDim.x + threadIdx.x) >> 6);
    int lane = threadIdx.x & 63;
    if (node >= N) return;
    int sub = lane >> 5, ch2 = lane & 31;   // lane covers channels 2*ch2, 2*ch2+1
    unsigned int start = rowptr[node] + blockOff[node >> 11];
    unsigned int cn = cnt[node];
    unsigned int iters = (cn + 7u) >> 3;   // 8 edges per iter (4 per half-wave)
    const uint4* sp = (const uint4*)(srcIdx + start + sub * 4);
    unsigned int sent = (unsigned int)N;
    float acc0 = 0.f, acc1 = 0.f;
    for (unsigned int it = 0; it < iters; ++it) {
        uint4 iv = sp[it * 2];
        unsigned int slot = it * 8u + (unsigned int)sub * 4u;
        unsigned int i0 = (slot + 0u < cn) ? iv.x : sent;
        unsigned int i1 = (slot + 1u < cn) ? iv.y : sent;
        unsigned int i2 = (slot + 2u < cn) ? iv.z : sent;
        unsigned int i3 = (slot + 3u < cn) ? iv.w : sent;
        float d0 = dinv[i0], d1 = dinv[i1], d2 = dinv[i2], d3 = dinv[i3];
        unsigned int u0 = *(const unsigned int*)(hs + (size_t)i0 * OUT_CH + 2 * ch2);
        unsigned int u1 = *(const unsigned int*)(hs + (size_t)i1 * OUT_CH + 2 * ch2);
        unsigned int u2 = *(const unsigned int*)(hs + (size_t)i2 * OUT_CH + 2 * ch2);
        unsigned int u3 = *(const unsigned int*)(hs + (size_t)i3 * OUT_CH + 2 * ch2);
        acc0 += bflo(u0) * d0 + bflo(u1) * d1 + bflo(u2) * d2 + bflo(u3) * d3;
        acc1 += bfhi(u0) * d0 + bfhi(u1) * d1 + bfhi(u2) * d2 + bfhi(u3) * d3;
    }
    acc0 += __shfl_xor(acc0, 32, 64);
    acc1 += __shfl_xor(acc1, 32, 64);
    // self-loop term: + hs[node]*dinv[node]; whole thing scaled by dinv[node]
    float di = dinv[node];
    unsigned int us = *(const unsigned int*)(hs + (size_t)node * OUT_CH + 2 * ch2);
    acc0 = fmaf(bflo(us), di, acc0);
    acc1 = fmaf(bfhi(us), di, acc1);
    float2 bb = *(const float2*)(bias + 2 * ch2);
    float v0 = fmaf(acc0, di, bb.x);
    float v1 = fmaf(acc1, di, bb.y);
    // log_softmax over 64 channels; each half-wave holds all channels (2/lane over 32 lanes)
    float mx = fmaxf(v0, v1);
#pragma unroll
    for (int off = 16; off > 0; off >>= 1) mx = fmaxf(mx, __shfl_xor(mx, off, 64));
    float s = expf(v0 - mx) + expf(v1 - mx);
#pragma unroll
    for (int off = 16; off > 0; off >>= 1) s += __shfl_xor(s, off, 64);
    float ls = logf(s);
    if (sub == 0) {
        float2 o = {v0 - mx - ls, v1 - mx - ls};
        *(float2*)(out + (size_t)node * OUT_CH + 2 * ch2) = o;
    }
}

extern "C" void kernel_launch(void* const* d_in, const int* in_sizes, int n_in,
                              void* d_out, int out_size, void* d_ws, size_t ws_size,
                              hipStream_t stream) {
    const float* x  = (const float*)d_in[0];
    const int*   ei = (const int*)d_in[1];
    const float* W  = (const float*)d_in[2];
    const float* b  = (const float*)d_in[3];
    float* out = (float*)d_out;

    const int N = in_sizes[0] / IN_CH;   // 100000
    const int E = in_sizes[1] / 2;       // 1600000
    const int NBLK = (N + SCAN_CHUNK - 1) / SCAN_CHUNK;  // 49
    const int NW = (N + 3) / 4;          // 25000 packed histogram words

    char* ws = (char*)d_ws;
    size_t o = 0;
    unsigned int* cnt      = (unsigned int*)(ws + o); o += (size_t)N * 4;
    unsigned int* rowptr   = (unsigned int*)(ws + o); o += (size_t)N * 4;
    unsigned int* blockSums= (unsigned int*)(ws + o); o += 256;
    unsigned int* blockOff = (unsigned int*)(ws + o); o += 256;
    float*        dinv     = (float*)(ws + o);        o += ((size_t)(N + 1) * 4 + 15) & ~15ull;
    // hist8 (G_PART planes of NW words) aliases srcIdx: hist8 dead after reduce_kernel,
    // srcIdx written only in fill_kernel (after reduce). Region = max of the two.
    size_t histBytes   = (size_t)G_PART * NW * 4;
    size_t srcIdxBytes = ((size_t)E + 3u * (size_t)N + 64) * 4;
    unsigned int* hist8    = (unsigned int*)(ws + o);
    unsigned int* srcIdx   = (unsigned int*)(ws + o); o += (histBytes > srcIdxBytes ? histBytes : srcIdxBytes);
    unsigned int* pre8     = (unsigned int*)(ws + o); o += histBytes;
    unsigned short* Wt     = (unsigned short*)(ws + o); o += (size_t)IN_CH * OUT_CH * 2;
    unsigned short* hs     = (unsigned short*)(ws + o); o += (size_t)(N + 1) * OUT_CH * 2;

    const int GB = (N + 63) / 64;                 // gemm blocks (4 waves * 16 rows) = 1563

    prep_kernel<<<129, 256, 0, stream>>>(W, Wt, hs, dinv, N);
    histo_kernel<<<G_PART, 256, 0, stream>>>(ei + E, hist8, N, E);
    gemm_kernel<<<GB, 256, 0, stream>>>(x, Wt, hs, N);
    reduce_kernel<<<(NW + 255) / 256, 256, 0, stream>>>(hist8, pre8, cnt, N);
    scan_a<<<NBLK, 256, 0, stream>>>(cnt, dinv, rowptr, blockSums, N);
    scan_b<<<1, 64, 0, stream>>>(blockSums, blockOff, NBLK);
    fill_kernel<<<G_PART, 256, 0, stream>>>(ei, rowptr, blockOff, pre8, srcIdx, N, E);
    gather_kernel<<<((size_t)N * 64 + 255) / 256, 256, 0, stream>>>(srcIdx, rowptr, blockOff, cnt, dinv, hs, b, out, N);
}

// Round 4
// 476.052 us; speedup vs baseline: 1.0794x; 1.0647x over previous
//
#include <hip/hip_runtime.h>
#include <hip/hip_bf16.h>

#define IN_CH 512
#define OUT_CH 64
#define SCAN_CHUNK 2048   // 256 threads * 8 elements
#define G_PART 256        // edge partitions (one block each in histo/fill)
#define NW_MAX 25088      // LDS words: ceil(N/4), N<=100352
#define BM 64             // gemm rows per block
#define BK 64             // gemm K-chunk (floats)
#define STRIPS 16         // reduce: strips of G_PART/STRIPS planes

typedef __attribute__((ext_vector_type(8))) short short8;
typedef __attribute__((ext_vector_type(4))) float f32x4;

static __device__ __forceinline__ unsigned short bf16bits(float f) {
    __hip_bfloat16 h = __float2bfloat16(f);
    return *reinterpret_cast<unsigned short*>(&h);
}
static __device__ __forceinline__ float bflo(unsigned int u) {  // low ushort as bf16 -> f32
    return __uint_as_float(u << 16);
}
static __device__ __forceinline__ float bfhi(unsigned int u) {  // high ushort as bf16 -> f32
    return __uint_as_float(u & 0xffff0000u);
}

// --- prep: W[512][64] -> Wt[64][512] bf16; sentinel hs row N + dinv[N]=0 ---
__global__ void prep_kernel(const float* __restrict__ W, unsigned short* __restrict__ Wt,
                            unsigned short* __restrict__ hs, float* __restrict__ dinv, int N) {
    int b = blockIdx.x;
    if (b < 128) {
        int i = b * 256 + threadIdx.x;   // 32768
        int k = i >> 6, n = i & 63;
        Wt[n * IN_CH + k] = bf16bits(W[i]);
        return;
    }
    if (threadIdx.x < OUT_CH) hs[(size_t)N * OUT_CH + threadIdx.x] = 0;
    if (threadIdx.x == 0) dinv[N] = 0.f;
}

// --- MFMA GEMM with async global_load_lds double-buffered x staging. ---
// Block = 4 waves, BM=64 rows, K chunked by BK=64 floats. LDS 2*16KB.
// x-tile stored XOR-swizzled: LDS[r*64 + (k ^ ((r&7)<<3))] = x[row0+r][c0*64+k].
// gload_lds writes linearly (base+lane*16B), so the swizzle is folded into the
// per-lane GLOBAL source address (rule: both-sides-or-neither); ds_read XORs again.
__global__ void __launch_bounds__(256, 4) gemm_kernel(const float* __restrict__ x,
                                                      const unsigned short* __restrict__ Wt,
                                                      unsigned short* __restrict__ hs, int N) {
    __shared__ float xs[2][BM * BK];
    const int t = threadIdx.x;
    const int w = t >> 6, lane = t & 63;
    const int row0 = (int)blockIdx.x * BM;
    const int m = lane & 15, q = lane >> 4;

    // staging geometry (per wave): instr j in [0,4): i = w*4+j covers LDS words
    // [i*256, i*256+256) = rows i*4..i*4+3, 16 lanes * 16B per row.
    // lane -> local row r = i*4 + (lane>>4), within-row word c = (lane&15)*4,
    // global k = c ^ ((r&7)<<3)  (inverse swizzle on the source).
    auto stage = [&](int buf, int c0) {
#pragma unroll
        for (int j = 0; j < 4; ++j) {
            int i = w * 4 + j;
            int r = i * 4 + (lane >> 4);
            int rg = row0 + r; rg = rg < N ? rg : N - 1;   // tail clamp (dup reads, discarded)
            int k = ((lane & 15) * 4) ^ ((r & 7) << 3);
            const float* src = x + (size_t)rg * IN_CH + c0 * BK + k;
            __builtin_amdgcn_global_load_lds(
                (const __attribute__((address_space(1))) void*)src,
                (__attribute__((address_space(3))) void*)&xs[buf][i * 256], 16, 0, 0);
        }
    };

    const unsigned short* wr = Wt + (size_t)m * IN_CH + q * 8;
    const int patm = (m & 7) << 3;
    f32x4 acc[4];
#pragma unroll
    for (int tt = 0; tt < 4; ++tt) acc[tt] = (f32x4){0.f, 0.f, 0.f, 0.f};

    stage(0, 0);
    int cur = 0;
    for (int c0 = 0; c0 < IN_CH / BK; ++c0) {   // 8 chunks
        __syncthreads();                         // drains vmcnt: buffer 'cur' ready; prev reads done
        if (c0 < IN_CH / BK - 1) stage(cur ^ 1, c0 + 1);   // async prefetch overlaps compute below
#pragma unroll
        for (int s = 0; s < 2; ++s) {            // two K=32 MFMA steps per chunk
            const float* ap = &xs[cur][(w * 16 + m) * BK + ((s * 32 + q * 8) ^ patm)];
            f32x4 a0 = *(const f32x4*)ap;
            f32x4 a1 = *(const f32x4*)(ap + 4);
            short8 af;
            af[0] = (short)bf16bits(a0[0]); af[1] = (short)bf16bits(a0[1]);
            af[2] = (short)bf16bits(a0[2]); af[3] = (short)bf16bits(a0[3]);
            af[4] = (short)bf16bits(a1[0]); af[5] = (short)bf16bits(a1[1]);
            af[6] = (short)bf16bits(a1[2]); af[7] = (short)bf16bits(a1[3]);
#pragma unroll
            for (int tt = 0; tt < 4; ++tt) {
                short8 bf = *(const short8*)(wr + (size_t)tt * 16 * IN_CH + c0 * BK + s * 32);
                acc[tt] = __builtin_amdgcn_mfma_f32_16x16x32_bf16(af, bf, acc[tt], 0, 0, 0);
            }
        }
        cur ^= 1;
    }
    // C/D layout: col = lane&15, row (within 16) = q*4 + reg
    int rbase = row0 + w * 16 + q * 4;
#pragma unroll
    for (int r = 0; r < 4; ++r) {
        int row = rbase + r;
        if (row < N) {
#pragma unroll
            for (int tt = 0; tt < 4; ++tt)
                hs[(size_t)row * OUT_CH + tt * 16 + m] = bf16bits(acc[tt][r]);
        }
    }
}

// --- histo: per-partition LDS 8-bit histogram (4 nodes/word), flushed with plain stores. ---
__global__ void __launch_bounds__(256) histo_kernel(const int* __restrict__ col,
                                                    unsigned int* __restrict__ hist8,
                                                    int N, int E) {
    __shared__ unsigned int h[NW_MAX];
    int NW = (N + 3) >> 2;
    int g = blockIdx.x;
    for (int w = threadIdx.x; w < NW; w += 256) h[w] = 0u;
    __syncthreads();
    int P = (E + G_PART - 1) / G_PART;
    int e0 = g * P, e1 = min(e0 + P, E);
    for (int e = e0 + (int)threadIdx.x; e < e1; e += 256) {
        int c = col[e];
        atomicAdd(&h[c >> 2], 1u << ((c & 3) * 8));   // ds_add, no return
    }
    __syncthreads();
    unsigned int* dst = hist8 + (size_t)g * NW;
    for (int w = threadIdx.x; w < NW; w += 256) dst[w] = h[w];
}

// --- reduce A: per-strip partial sums. thread (w, s): part[s][w] = sum of 16 planes. ---
// (replaces the old 256-deep dependent-chain reduce with 400K threads of 16 indep loads)
__global__ void reduce_a(const unsigned int* __restrict__ hist8,
                         unsigned int* __restrict__ part, int NW) {
    int w = blockIdx.x * 256 + threadIdx.x;
    int s = blockIdx.y;
    if (w >= NW) return;
    const unsigned int* hp = hist8 + (size_t)s * (G_PART / STRIPS) * NW + w;
    unsigned int v[G_PART / STRIPS];
#pragma unroll
    for (int g = 0; g < G_PART / STRIPS; ++g) v[g] = hp[(size_t)g * NW];
    unsigned int sum = 0;
#pragma unroll
    for (int g = 0; g < G_PART / STRIPS; ++g) sum += v[g];
    part[(size_t)s * NW + w] = sum;
}

// --- reduce B: thread (w, s): strip base from part prefix, then exclusive prefix planes
//     pre8[g][w] within the strip. s==STRIPS-1 also emits final counts cnt. ---
__global__ void reduce_b(const unsigned int* __restrict__ hist8,
                         const unsigned int* __restrict__ part,
                         unsigned int* __restrict__ pre8,
                         unsigned int* __restrict__ cnt, int N, int NW) {
    int w = blockIdx.x * 256 + threadIdx.x;
    int s = blockIdx.y;
    if (w >= NW) return;
    unsigned int ps[STRIPS];
#pragma unroll
    for (int k = 0; k < STRIPS; ++k) ps[k] = part[(size_t)k * NW + w];
    unsigned int base = 0;
    for (int k = 0; k < s; ++k) base += ps[k];
    const unsigned int* hp = hist8 + (size_t)s * (G_PART / STRIPS) * NW + w;
    unsigned int* pp = pre8 + (size_t)s * (G_PART / STRIPS) * NW + w;
    unsigned int v[G_PART / STRIPS];
#pragma unroll
    for (int g = 0; g < G_PART / STRIPS; ++g) v[g] = hp[(size_t)g * NW];
    unsigned int run = base;
#pragma unroll
    for (int g = 0; g < G_PART / STRIPS; ++g) { pp[(size_t)g * NW] = run; run += v[g]; }
    if (s == STRIPS - 1) {
        int n0 = w * 4;
#pragma unroll
        for (int j = 0; j < 4; ++j)
            if (n0 + j < N) cnt[n0 + j] = (run >> (j * 8)) & 0xffu;
    }
}

// --- scan A: per-chunk exclusive scan of counts padded to mult of 4; also dinv ---
__global__ void scan_a(const unsigned int* __restrict__ cnt, float* __restrict__ dinv,
                       unsigned int* __restrict__ rowptr, unsigned int* __restrict__ blockSums, int N) {
    __shared__ unsigned int wsum[4];
    int t = threadIdx.x, b = blockIdx.x;
    int base = b * SCAN_CHUNK + t * 8;
    unsigned int p[8];
    unsigned int run = 0;
#pragma unroll
    for (int j = 0; j < 8; ++j) {
        unsigned int v = (base + j < N) ? cnt[base + j] : 0u;
        if (base + j < N) dinv[base + j] = rsqrtf((float)(v + 1u));
        p[j] = run;
        run += (v + 3u) & ~3u;   // pad to mult of 4 -> segment starts uint4-aligned
    }
    unsigned int s = run;
    unsigned int si = s;
#pragma unroll
    for (int off = 1; off < 64; off <<= 1) {
        unsigned int o = __shfl_up(si, off, 64);
        if ((t & 63) >= off) si += o;
    }
    if ((t & 63) == 63) wsum[t >> 6] = si;
    __syncthreads();
    unsigned int woff = 0;
    int w = t >> 6;
    for (int k = 0; k < w; ++k) woff += wsum[k];
    unsigned int exc = woff + si - s;
#pragma unroll
    for (int j = 0; j < 8; ++j)
        if (base + j < N) rowptr[base + j] = exc + p[j];
    if (t == 255) blockSums[b] = woff + si;
}

// --- scan B: exclusive scan of block totals (single wave, nb<=64) ---
__global__ void scan_b(const unsigned int* __restrict__ blockSums, unsigned int* __restrict__ blockOff, int nb) {
    int t = threadIdx.x;
    unsigned int s = (t < nb) ? blockSums[t] : 0u;
    unsigned int si = s;
#pragma unroll
    for (int off = 1; off < 64; off <<= 1) {
        unsigned int o = __shfl_up(si, off, 64);
        if (t >= off) si += o;
    }
    blockOff[t] = si - s;
}

// --- fill: same partitioning as histo; LDS packed-byte cursors (ds_add_rtn). ---
__global__ void __launch_bounds__(256) fill_kernel(const int* __restrict__ ei,
                                                   const unsigned int* __restrict__ rowptr,
                                                   const unsigned int* __restrict__ blockOff,
                                                   const unsigned int* __restrict__ pre8,
                                                   unsigned int* __restrict__ srcIdx,
                                                   int N, int E) {
    __shared__ unsigned int cur[NW_MAX];
    int NW = (N + 3) >> 2;
    int g = blockIdx.x;
    for (int w = threadIdx.x; w < NW; w += 256) cur[w] = 0u;
    __syncthreads();
    const unsigned int* pre = pre8 + (size_t)g * NW;
    int P = (E + G_PART - 1) / G_PART;
    int e0 = g * P, e1 = min(e0 + P, E);
#pragma unroll 4
    for (int e = e0 + (int)threadIdx.x; e < e1; e += 256) {
        int r = ei[e];        // source
        int c = ei[E + e];    // target
        int sh = (c & 3) * 8;
        unsigned int old = atomicAdd(&cur[c >> 2], 1u << sh);
        unsigned int rank = (old >> sh) & 0xffu;
        unsigned int base = (pre[c >> 2] >> sh) & 0xffu;
        unsigned int pos = rowptr[c] + blockOff[c >> 11] + base + rank;
        srcIdx[pos] = (unsigned int)r;
    }
}

// --- fused gather + self + bias + log_softmax. One wave/node; half-waves cover 4 edges each. ---
__global__ void __launch_bounds__(256) gather_kernel(const unsigned int* __restrict__ srcIdx,
                                                     const unsigned int* __restrict__ rowptr,
                                                     const unsigned int* __restrict__ blockOff,
                                                     const unsigned int* __restrict__ cnt,
                                                     const float* __restrict__ dinv,
                                                     const unsigned short* __restrict__ hs,
                                                     const float* __restrict__ bias,
                                                     float* __restrict__ out, int N) {
    int node = (int)((blockIdx.x * (unsigned long long)blockDim.x + threadIdx.x) >> 6);
    int lane = threadIdx.x & 63;
    if (node >= N) return;
    int sub = lane >> 5, ch2 = lane & 31;   // lane covers channels 2*ch2, 2*ch2+1
    unsigned int start = rowptr[node] + blockOff[node >> 11];
    unsigned int cn = cnt[node];
    unsigned int iters = (cn + 7u) >> 3;   // 8 edges per iter (4 per half-wave)
    const uint4* sp = (const uint4*)(srcIdx + start + sub * 4);
    unsigned int sent = (unsigned int)N;
    float acc0 = 0.f, acc1 = 0.f;
    for (unsigned int it = 0; it < iters; ++it) {
        uint4 iv = sp[it * 2];
        unsigned int slot = it * 8u + (unsigned int)sub * 4u;
        unsigned int i0 = (slot + 0u < cn) ? iv.x : sent;
        unsigned int i1 = (slot + 1u < cn) ? iv.y : sent;
        unsigned int i2 = (slot + 2u < cn) ? iv.z : sent;
        unsigned int i3 = (slot + 3u < cn) ? iv.w : sent;
        float d0 = dinv[i0], d1 = dinv[i1], d2 = dinv[i2], d3 = dinv[i3];
        unsigned int u0 = *(const unsigned int*)(hs + (size_t)i0 * OUT_CH + 2 * ch2);
        unsigned int u1 = *(const unsigned int*)(hs + (size_t)i1 * OUT_CH + 2 * ch2);
        unsigned int u2 = *(const unsigned int*)(hs + (size_t)i2 * OUT_CH + 2 * ch2);
        unsigned int u3 = *(const unsigned int*)(hs + (size_t)i3 * OUT_CH + 2 * ch2);
        acc0 += bflo(u0) * d0 + bflo(u1) * d1 + bflo(u2) * d2 + bflo(u3) * d3;
        acc1 += bfhi(u0) * d0 + bfhi(u1) * d1 + bfhi(u2) * d2 + bfhi(u3) * d3;
    }
    acc0 += __shfl_xor(acc0, 32, 64);
    acc1 += __shfl_xor(acc1, 32, 64);
    float di = dinv[node];
    unsigned int us = *(const unsigned int*)(hs + (size_t)node * OUT_CH + 2 * ch2);
    acc0 = fmaf(bflo(us), di, acc0);
    acc1 = fmaf(bfhi(us), di, acc1);
    float2 bb = *(const float2*)(bias + 2 * ch2);
    float v0 = fmaf(acc0, di, bb.x);
    float v1 = fmaf(acc1, di, bb.y);
    float mx = fmaxf(v0, v1);
#pragma unroll
    for (int off = 16; off > 0; off >>= 1) mx = fmaxf(mx, __shfl_xor(mx, off, 64));
    float s = expf(v0 - mx) + expf(v1 - mx);
#pragma unroll
    for (int off = 16; off > 0; off >>= 1) s += __shfl_xor(s, off, 64);
    float ls = logf(s);
    if (sub == 0) {
        float2 o = {v0 - mx - ls, v1 - mx - ls};
        *(float2*)(out + (size_t)node * OUT_CH + 2 * ch2) = o;
    }
}

extern "C" void kernel_launch(void* const* d_in, const int* in_sizes, int n_in,
                              void* d_out, int out_size, void* d_ws, size_t ws_size,
                              hipStream_t stream) {
    const float* x  = (const float*)d_in[0];
    const int*   ei = (const int*)d_in[1];
    const float* W  = (const float*)d_in[2];
    const float* b  = (const float*)d_in[3];
    float* out = (float*)d_out;

    const int N = in_sizes[0] / IN_CH;   // 100000
    const int E = in_sizes[1] / 2;       // 1600000
    const int NBLK = (N + SCAN_CHUNK - 1) / SCAN_CHUNK;  // 49
    const int NW = (N + 3) / 4;          // 25000 packed histogram words

    char* ws = (char*)d_ws;
    size_t o = 0;
    unsigned int* cnt      = (unsigned int*)(ws + o); o += (size_t)N * 4;
    unsigned int* rowptr   = (unsigned int*)(ws + o); o += (size_t)N * 4;
    unsigned int* blockSums= (unsigned int*)(ws + o); o += 256;
    unsigned int* blockOff = (unsigned int*)(ws + o); o += 256;
    float*        dinv     = (float*)(ws + o);        o += ((size_t)(N + 1) * 4 + 15) & ~15ull;
    // hist8 (G_PART planes of NW words) aliases srcIdx: hist8 dead after reduce_b,
    // srcIdx written only in fill_kernel (after reduce_b). Region = max of the two.
    size_t histBytes   = (size_t)G_PART * NW * 4;
    size_t srcIdxBytes = ((size_t)E + 3u * (size_t)N + 64) * 4;
    unsigned int* hist8    = (unsigned int*)(ws + o);
    unsigned int* srcIdx   = (unsigned int*)(ws + o); o += (histBytes > srcIdxBytes ? histBytes : srcIdxBytes);
    unsigned int* pre8     = (unsigned int*)(ws + o); o += histBytes;
    unsigned int* part     = (unsigned int*)(ws + o); o += (size_t)STRIPS * NW * 4;
    unsigned short* Wt     = (unsigned short*)(ws + o); o += (size_t)IN_CH * OUT_CH * 2;
    unsigned short* hs     = (unsigned short*)(ws + o); o += (size_t)(N + 1) * OUT_CH * 2;

    const int GB = (N + BM - 1) / BM;             // gemm blocks = 1563
    const dim3 RG((NW + 255) / 256, STRIPS);

    prep_kernel<<<129, 256, 0, stream>>>(W, Wt, hs, dinv, N);
    gemm_kernel<<<GB, 256, 0, stream>>>(x, Wt, hs, N);
    histo_kernel<<<G_PART, 256, 0, stream>>>(ei + E, hist8, N, E);
    reduce_a<<<RG, 256, 0, stream>>>(hist8, part, NW);
    reduce_b<<<RG, 256, 0, stream>>>(hist8, part, pre8, cnt, N, NW);
    scan_a<<<NBLK, 256, 0, stream>>>(cnt, dinv, rowptr, blockSums, N);
    scan_b<<<1, 64, 0, stream>>>(blockSums, blockOff, NBLK);
    fill_kernel<<<G_PART, 256, 0, stream>>>(ei, rowptr, blockOff, pre8, srcIdx, N, E);
    gather_kernel<<<((size_t)N * 64 + 255) / 256, 256, 0, stream>>>(srcIdx, rowptr, blockOff, cnt, dinv, hs, b, out, N);
}

// Round 5
// 452.154 us; speedup vs baseline: 1.1365x; 1.0529x over previous
//
#include <hip/hip_runtime.h>
#include <hip/hip_bf16.h>

#define IN_CH 512
#define OUT_CH 64
#define SCAN_CHUNK 2048   // 256 threads * 8 elements
#define G_PART 256        // edge partitions (one block each in histo/fill)
#define NW_MAX 25088      // LDS words: ceil(N/4), N<=100352
#define BM 64             // gemm rows per block
#define BK 64             // gemm K-chunk (floats)

typedef __attribute__((ext_vector_type(8))) short short8;
typedef __attribute__((ext_vector_type(4))) float f32x4;

static __device__ __forceinline__ unsigned short bf16bits(float f) {
    __hip_bfloat16 h = __float2bfloat16(f);
    return *reinterpret_cast<unsigned short*>(&h);
}
static __device__ __forceinline__ float bflo(unsigned int u) {  // low ushort as bf16 -> f32
    return __uint_as_float(u << 16);
}
static __device__ __forceinline__ float bfhi(unsigned int u) {  // high ushort as bf16 -> f32
    return __uint_as_float(u & 0xffff0000u);
}

// --- prep: W[512][64] -> Wt[64][512] bf16; sentinel hs row N + dinv[N]=0 ---
__global__ void prep_kernel(const float* __restrict__ W, unsigned short* __restrict__ Wt,
                            unsigned short* __restrict__ hs, float* __restrict__ dinv, int N) {
    int b = blockIdx.x;
    if (b < 128) {
        int i = b * 256 + threadIdx.x;   // 32768
        int k = i >> 6, n = i & 63;
        Wt[n * IN_CH + k] = bf16bits(W[i]);
        return;
    }
    if (threadIdx.x < OUT_CH) hs[(size_t)N * OUT_CH + threadIdx.x] = 0;
    if (threadIdx.x == 0) dinv[N] = 0.f;
}

// --- MFMA GEMM with async global_load_lds double-buffered x staging. ---
// LDS layout: within row r (64 floats = 16 quads), quad Lq holds global quad Lq ^ (r&7)
// (XOR on quad-bits 0-2 -> bank index bits 2-4 -> ds_read_b128 spreads 8 lanes per
// bank-quad = conflict-free). gload_lds writes linearly, so the inverse swizzle is
// folded into the per-lane GLOBAL source address (both-sides-or-neither rule).
__global__ void __launch_bounds__(256, 4) gemm_kernel(const float* __restrict__ x,
                                                      const unsigned short* __restrict__ Wt,
                                                      unsigned short* __restrict__ hs, int N) {
    __shared__ float xs[2][BM * BK];
    const int t = threadIdx.x;
    const int w = t >> 6, lane = t & 63;
    const int row0 = (int)blockIdx.x * BM;
    const int m = lane & 15, q = lane >> 4;

    // per wave: instr j covers LDS words [i*256, i*256+256) = rows i*4..i*4+3.
    // lane -> local row r = i*4 + (lane>>4), LDS quad (lane&15);
    // global quad = (lane&15) ^ (r&7)  (inverse swizzle on the source).
    auto stage = [&](int buf, int c0) {
#pragma unroll
        for (int j = 0; j < 4; ++j) {
            int i = w * 4 + j;
            int r = i * 4 + (lane >> 4);
            int rg = row0 + r; rg = rg < N ? rg : N - 1;   // tail clamp (dup reads, discarded)
            int k = ((lane & 15) ^ (r & 7)) << 2;
            const float* src = x + (size_t)rg * IN_CH + c0 * BK + k;
            __builtin_amdgcn_global_load_lds(
                (const __attribute__((address_space(1))) void*)src,
                (__attribute__((address_space(3))) void*)&xs[buf][i * 256], 16, 0, 0);
        }
    };

    const unsigned short* wr = Wt + (size_t)m * IN_CH + q * 8;
    const int pm = m & 7;
    const int rowbase = (w * 16 + m) * BK;
    f32x4 acc[4];
#pragma unroll
    for (int tt = 0; tt < 4; ++tt) acc[tt] = (f32x4){0.f, 0.f, 0.f, 0.f};

    stage(0, 0);
    int cur = 0;
    for (int c0 = 0; c0 < IN_CH / BK; ++c0) {   // 8 chunks
        __syncthreads();                         // drains vmcnt: buffer 'cur' ready; prev reads done
        if (c0 < IN_CH / BK - 1) stage(cur ^ 1, c0 + 1);   // async prefetch overlaps compute below
#pragma unroll
        for (int s = 0; s < 2; ++s) {            // two K=32 MFMA steps per chunk
            int qi = s * 8 + q * 2;              // global quad of first f32x4
            f32x4 a0 = *(const f32x4*)&xs[cur][rowbase + (((qi    ) ^ pm) << 2)];
            f32x4 a1 = *(const f32x4*)&xs[cur][rowbase + (((qi + 1) ^ pm) << 2)];
            short8 af;
            af[0] = (short)bf16bits(a0[0]); af[1] = (short)bf16bits(a0[1]);
            af[2] = (short)bf16bits(a0[2]); af[3] = (short)bf16bits(a0[3]);
            af[4] = (short)bf16bits(a1[0]); af[5] = (short)bf16bits(a1[1]);
            af[6] = (short)bf16bits(a1[2]); af[7] = (short)bf16bits(a1[3]);
#pragma unroll
            for (int tt = 0; tt < 4; ++tt) {
                short8 bf = *(const short8*)(wr + (size_t)tt * 16 * IN_CH + c0 * BK + s * 32);
                acc[tt] = __builtin_amdgcn_mfma_f32_16x16x32_bf16(af, bf, acc[tt], 0, 0, 0);
            }
        }
        cur ^= 1;
    }
    // C/D layout: col = lane&15, row (within 16) = q*4 + reg
    int rbase = row0 + w * 16 + q * 4;
#pragma unroll
    for (int r = 0; r < 4; ++r) {
        int row = rbase + r;
        if (row < N) {
#pragma unroll
            for (int tt = 0; tt < 4; ++tt)
                hs[(size_t)row * OUT_CH + tt * 16 + m] = bf16bits(acc[tt][r]);
        }
    }
}

// --- histo: per-partition LDS 8-bit histogram (4 nodes/word), flushed with plain stores. ---
__global__ void __launch_bounds__(256) histo_kernel(const int* __restrict__ col,
                                                    unsigned int* __restrict__ hist8,
                                                    int N, int E) {
    __shared__ unsigned int h[NW_MAX];
    int NW = (N + 3) >> 2;
    int g = blockIdx.x;
    for (int w = threadIdx.x; w < NW; w += 256) h[w] = 0u;
    __syncthreads();
    int P = (E + G_PART - 1) / G_PART;
    int e0 = g * P, e1 = min(e0 + P, E);
    for (int e = e0 + (int)threadIdx.x; e < e1; e += 256) {
        int c = col[e];
        atomicAdd(&h[c >> 2], 1u << ((c & 3) * 8));   // ds_add, no return
    }
    __syncthreads();
    unsigned int* dst = hist8 + (size_t)g * NW;
    for (int w = threadIdx.x; w < NW; w += 256) dst[w] = h[w];
}

// --- reduce: ONE kernel. Block = 64 words x all 256 planes. Wave wv holds its 64
//     plane-values in registers (fully unrolled -> static idx), coalesced 256B rows
//     both ways; cross-wave per-word prefix via LDS. Emits pre8 planes + cnt. ---
__global__ void __launch_bounds__(256) reduce_kernel(const unsigned int* __restrict__ hist8,
                                                     unsigned int* __restrict__ pre8,
                                                     unsigned int* __restrict__ cnt,
                                                     int N, int NW) {
    __shared__ unsigned int wsum[4][64];
    int lane = threadIdx.x & 63, wv = threadIdx.x >> 6;
    int w = (int)blockIdx.x * 64 + lane;
    bool act = w < NW;
    const unsigned int* hp = hist8 + (size_t)wv * 64 * NW + w;
    unsigned int v[64];
#pragma unroll
    for (int j = 0; j < 64; ++j) v[j] = act ? hp[(size_t)j * NW] : 0u;
    unsigned int s = 0;
#pragma unroll
    for (int j = 0; j < 64; ++j) s += v[j];
    wsum[wv][lane] = s;
    __syncthreads();
    unsigned int run = 0;
    for (int k = 0; k < wv; ++k) run += wsum[k][lane];
    if (act) {
        unsigned int* pp = pre8 + (size_t)wv * 64 * NW + w;
#pragma unroll
        for (int j = 0; j < 64; ++j) { pp[(size_t)j * NW] = run; run += v[j]; }
        if (wv == 3) {   // run = total over all 256 planes (packed bytes, carry-free)
            int n0 = w * 4;
            if (n0 + 3 < N) {
                uint4 cv = {run & 0xffu, (run >> 8) & 0xffu, (run >> 16) & 0xffu, (run >> 24) & 0xffu};
                *(uint4*)&cnt[n0] = cv;
            } else {
                for (int j = 0; j < 4 && n0 + j < N; ++j) cnt[n0 + j] = (run >> (j * 8)) & 0xffu;
            }
        }
    }
}

// --- scan A: exclusive scan of padded counts; packs cnt into rowptr top byte; also dinv ---
__global__ void scan_a(const unsigned int* __restrict__ cnt, float* __restrict__ dinv,
                       unsigned int* __restrict__ rowptr, unsigned int* __restrict__ blockSums, int N) {
    __shared__ unsigned int wsum[4];
    int t = threadIdx.x, b = blockIdx.x;
    int base = b * SCAN_CHUNK + t * 8;
    unsigned int p[8], vv[8];
    unsigned int run = 0;
#pragma unroll
    for (int j = 0; j < 8; ++j) {
        unsigned int v = (base + j < N) ? cnt[base + j] : 0u;
        if (base + j < N) dinv[base + j] = rsqrtf((float)(v + 1u));
        vv[j] = v;
        p[j] = run;
        run += (v + 3u) & ~3u;   // pad to mult of 4 -> segment starts uint4-aligned
    }
    unsigned int s = run;
    unsigned int si = s;
#pragma unroll
    for (int off = 1; off < 64; off <<= 1) {
        unsigned int o = __shfl_up(si, off, 64);
        if ((t & 63) >= off) si += o;
    }
    if ((t & 63) == 63) wsum[t >> 6] = si;
    __syncthreads();
    unsigned int woff = 0;
    int w = t >> 6;
    for (int k = 0; k < w; ++k) woff += wsum[k];
    unsigned int exc = woff + si - s;
#pragma unroll
    for (int j = 0; j < 8; ++j)
        if (base + j < N) rowptr[base + j] = (exc + p[j]) | (vv[j] << 24);   // pack cnt in top byte
    if (t == 255) blockSums[b] = woff + si;
}

// --- scan B: exclusive scan of block totals (single wave, nb<=64) ---
__global__ void scan_b(const unsigned int* __restrict__ blockSums, unsigned int* __restrict__ blockOff, int nb) {
    int t = threadIdx.x;
    unsigned int s = (t < nb) ? blockSums[t] : 0u;
    unsigned int si = s;
#pragma unroll
    for (int off = 1; off < 64; off <<= 1) {
        unsigned int o = __shfl_up(si, off, 64);
        if (t >= off) si += o;
    }
    blockOff[t] = si - s;
}

// --- fill: LDS cursors PRELOADED with this partition's pre8 plane (coalesced);
//     atomicAdd then returns base+rank directly -> no per-edge global pre read,
//     no zero pass. Bytes never carry (base+rank <= deg < 256). ---
__global__ void __launch_bounds__(256) fill_kernel(const int* __restrict__ ei,
                                                   const unsigned int* __restrict__ rowptr,
                                                   const unsigned int* __restrict__ blockOff,
                                                   const unsigned int* __restrict__ pre8,
                                                   unsigned int* __restrict__ srcIdx,
                                                   int N, int E) {
    __shared__ unsigned int cur[NW_MAX];
    int NW = (N + 3) >> 2;
    int g = blockIdx.x;
    const unsigned int* pre = pre8 + (size_t)g * NW;
    for (int w = threadIdx.x; w < NW; w += 256) cur[w] = pre[w];
    __syncthreads();
    int P = (E + G_PART - 1) / G_PART;
    int e0 = g * P, e1 = min(e0 + P, E);
#pragma unroll 4
    for (int e = e0 + (int)threadIdx.x; e < e1; e += 256) {
        int r = ei[e];        // source
        int c = ei[E + e];    // target
        int sh = (c & 3) * 8;
        unsigned int old = atomicAdd(&cur[c >> 2], 1u << sh);
        unsigned int pos = (rowptr[c] & 0xffffffu) + blockOff[c >> 11] + ((old >> sh) & 0xffu);
        srcIdx[pos] = (unsigned int)r;
    }
}

// --- fused gather + self + bias + log_softmax. One wave/node; half-waves cover 4 edges each.
//     rowptr packs {cnt:8, offset:24}. hs UNSCALED; tail slots clamp to sentinel N. ---
__global__ void __launch_bounds__(256) gather_kernel(const unsigned int* __restrict__ srcIdx,
                                                     const unsigned int* __restrict__ rowptr,
                                                     const unsigned int* __restrict__ blockOff,
                                                     const float* __restrict__ dinv,
                                                     const unsigned short* __restrict__ hs,
                                                     const float* __restrict__ bias,
                                                     float* __restrict__ out, int N) {
    int node = (int)((blockIdx.x * (unsigned long long)blockDim.x + threadIdx.x) >> 6);
    int lane = threadIdx.x & 63;
    if (node >= N) return;
    int sub = lane >> 5, ch2 = lane & 31;   // lane covers channels 2*ch2, 2*ch2+1
    unsigned int rp = rowptr[node];
    unsigned int start = (rp & 0xffffffu) + blockOff[node >> 11];
    unsigned int cn = rp >> 24;
    unsigned int iters = (cn + 7u) >> 3;   // 8 edges per iter (4 per half-wave)
    const uint4* sp = (const uint4*)(srcIdx + start + sub * 4);
    unsigned int sent = (unsigned int)N;
    float acc0 = 0.f, acc1 = 0.f;
    for (unsigned int it = 0; it < iters; ++it) {
        uint4 iv = sp[it * 2];
        unsigned int slot = it * 8u + (unsigned int)sub * 4u;
        unsigned int i0 = (slot + 0u < cn) ? iv.x : sent;
        unsigned int i1 = (slot + 1u < cn) ? iv.y : sent;
        unsigned int i2 = (slot + 2u < cn) ? iv.z : sent;
        unsigned int i3 = (slot + 3u < cn) ? iv.w : sent;
        float d0 = dinv[i0], d1 = dinv[i1], d2 = dinv[i2], d3 = dinv[i3];
        unsigned int u0 = *(const unsigned int*)(hs + (size_t)i0 * OUT_CH + 2 * ch2);
        unsigned int u1 = *(const unsigned int*)(hs + (size_t)i1 * OUT_CH + 2 * ch2);
        unsigned int u2 = *(const unsigned int*)(hs + (size_t)i2 * OUT_CH + 2 * ch2);
        unsigned int u3 = *(const unsigned int*)(hs + (size_t)i3 * OUT_CH + 2 * ch2);
        acc0 += bflo(u0) * d0 + bflo(u1) * d1 + bflo(u2) * d2 + bflo(u3) * d3;
        acc1 += bfhi(u0) * d0 + bfhi(u1) * d1 + bfhi(u2) * d2 + bfhi(u3) * d3;
    }
    acc0 += __shfl_xor(acc0, 32, 64);
    acc1 += __shfl_xor(acc1, 32, 64);
    float di = dinv[node];
    unsigned int us = *(const unsigned int*)(hs + (size_t)node * OUT_CH + 2 * ch2);
    acc0 = fmaf(bflo(us), di, acc0);
    acc1 = fmaf(bfhi(us), di, acc1);
    float2 bb = *(const float2*)(bias + 2 * ch2);
    float v0 = fmaf(acc0, di, bb.x);
    float v1 = fmaf(acc1, di, bb.y);
    float mx = fmaxf(v0, v1);
#pragma unroll
    for (int off = 16; off > 0; off >>= 1) mx = fmaxf(mx, __shfl_xor(mx, off, 64));
    float s = expf(v0 - mx) + expf(v1 - mx);
#pragma unroll
    for (int off = 16; off > 0; off >>= 1) s += __shfl_xor(s, off, 64);
    float ls = logf(s);
    if (sub == 0) {
        float2 o = {v0 - mx - ls, v1 - mx - ls};
        *(float2*)(out + (size_t)node * OUT_CH + 2 * ch2) = o;
    }
}

extern "C" void kernel_launch(void* const* d_in, const int* in_sizes, int n_in,
                              void* d_out, int out_size, void* d_ws, size_t ws_size,
                              hipStream_t stream) {
    const float* x  = (const float*)d_in[0];
    const int*   ei = (const int*)d_in[1];
    const float* W  = (const float*)d_in[2];
    const float* b  = (const float*)d_in[3];
    float* out = (float*)d_out;

    const int N = in_sizes[0] / IN_CH;   // 100000
    const int E = in_sizes[1] / 2;       // 1600000
    const int NBLK = (N + SCAN_CHUNK - 1) / SCAN_CHUNK;  // 49
    const int NW = (N + 3) / 4;          // 25000 packed histogram words

    char* ws = (char*)d_ws;
    size_t o = 0;
    unsigned int* cnt      = (unsigned int*)(ws + o); o += (size_t)N * 4;
    unsigned int* rowptr   = (unsigned int*)(ws + o); o += (size_t)N * 4;
    unsigned int* blockSums= (unsigned int*)(ws + o); o += 256;
    unsigned int* blockOff = (unsigned int*)(ws + o); o += 256;
    float*        dinv     = (float*)(ws + o);        o += ((size_t)(N + 1) * 4 + 15) & ~15ull;
    // hist8 (G_PART planes of NW words) aliases srcIdx: hist8 dead after reduce_kernel,
    // srcIdx written only in fill_kernel (after reduce). Region = max of the two.
    size_t histBytes   = (size_t)G_PART * NW * 4;
    size_t srcIdxBytes = ((size_t)E + 3u * (size_t)N + 64) * 4;
    unsigned int* hist8    = (unsigned int*)(ws + o);
    unsigned int* srcIdx   = (unsigned int*)(ws + o); o += (histBytes > srcIdxBytes ? histBytes : srcIdxBytes);
    unsigned int* pre8     = (unsigned int*)(ws + o); o += histBytes;
    unsigned short* Wt     = (unsigned short*)(ws + o); o += (size_t)IN_CH * OUT_CH * 2;
    unsigned short* hs     = (unsigned short*)(ws + o); o += (size_t)(N + 1) * OUT_CH * 2;

    const int GB = (N + BM - 1) / BM;             // gemm blocks = 1563

    prep_kernel<<<129, 256, 0, stream>>>(W, Wt, hs, dinv, N);
    gemm_kernel<<<GB, 256, 0, stream>>>(x, Wt, hs, N);
    histo_kernel<<<G_PART, 256, 0, stream>>>(ei + E, hist8, N, E);
    reduce_kernel<<<(NW + 63) / 64, 256, 0, stream>>>(hist8, pre8, cnt, N, NW);
    scan_a<<<NBLK, 256, 0, stream>>>(cnt, dinv, rowptr, blockSums, N);
    scan_b<<<1, 64, 0, stream>>>(blockSums, blockOff, NBLK);
    fill_kernel<<<G_PART, 256, 0, stream>>>(ei, rowptr, blockOff, pre8, srcIdx, N, E);
    gather_kernel<<<((size_t)N * 64 + 255) / 256, 256, 0, stream>>>(srcIdx, rowptr, blockOff, dinv, hs, b, out, N);
}

// Round 6
// 438.551 us; speedup vs baseline: 1.1717x; 1.0310x over previous
//
#include <hip/hip_runtime.h>
#include <hip/hip_bf16.h>

#define IN_CH 512
#define OUT_CH 64
#define SCAN_CHUNK 2048   // 256 threads * 8 elements
#define G_PART 256        // edge partitions
#define NQUAD 4           // node quadrants (histo/fill LDS = NW/4 words = 25KB)
#define NWQ_MAX 6272      // LDS words per quadrant: ceil(ceil(N/4)/4), N<=100352
#define BM 64             // gemm rows per block
#define BK 64             // gemm K-chunk (floats)

typedef __attribute__((ext_vector_type(8))) short short8;
typedef __attribute__((ext_vector_type(4))) float f32x4;

static __device__ __forceinline__ unsigned short bf16bits(float f) {
    __hip_bfloat16 h = __float2bfloat16(f);
    return *reinterpret_cast<unsigned short*>(&h);
}
static __device__ __forceinline__ float bflo(unsigned int u) {  // low ushort as bf16 -> f32
    return __uint_as_float(u << 16);
}
static __device__ __forceinline__ float bfhi(unsigned int u) {  // high ushort as bf16 -> f32
    return __uint_as_float(u & 0xffff0000u);
}

// --- prep: W[512][64] -> Wt[64][512] bf16; sentinel hs row N + dinv[N]=0 ---
__global__ void prep_kernel(const float* __restrict__ W, unsigned short* __restrict__ Wt,
                            unsigned short* __restrict__ hs, float* __restrict__ dinv, int N) {
    int b = blockIdx.x;
    if (b < 128) {
        int i = b * 256 + threadIdx.x;   // 32768
        int k = i >> 6, n = i & 63;
        Wt[n * IN_CH + k] = bf16bits(W[i]);
        return;
    }
    if (threadIdx.x < OUT_CH) hs[(size_t)N * OUT_CH + threadIdx.x] = 0;
    if (threadIdx.x == 0) dinv[N] = 0.f;
}

// --- FUSED: blocks [0,GB) = MFMA GEMM (async gload_lds double-buffer, XOR-swizzled);
//     blocks [GB, GB+G_PART*NQUAD) = histo over (edge-partition g, node-quadrant quad).
//     Independent work, complementary resources (gemm: L3/HBM-bound; histo: LDS-bound);
//     one dispatch overlaps them. LDS union 32KB keeps gemm at 4 blocks/CU. ---
__global__ void __launch_bounds__(256, 4) gemm_histo(const float* __restrict__ x,
                                                     const unsigned short* __restrict__ Wt,
                                                     unsigned short* __restrict__ hs, int N,
                                                     const int* __restrict__ col,
                                                     unsigned int* __restrict__ hist8,
                                                     int E, int GB) {
    __shared__ float xs[2][BM * BK];   // 32KB; histo path reuses as uint h[<=8192]

    if ((int)blockIdx.x >= GB) {
        // ---- histo quadrant block ----
        unsigned int* h = (unsigned int*)&xs[0][0];
        int NW = (N + 3) >> 2;
        int NWQ = (NW + NQUAD - 1) / NQUAD;
        int b = (int)blockIdx.x - GB;
        int g = b >> 2, quad = b & 3;
        int w0 = quad * NWQ, w1 = min(w0 + NWQ, NW);
        int nw = w1 - w0;
        for (int w = threadIdx.x; w < nw; w += 256) h[w] = 0u;
        __syncthreads();
        int P = (E + G_PART - 1) / G_PART;
        int e0 = g * P, e1 = min(e0 + P, E);
        for (int e = e0 + (int)threadIdx.x; e < e1; e += 256) {
            int c = col[e];
            int wq = c >> 2;
            if (wq >= w0 && wq < w1)
                atomicAdd(&h[wq - w0], 1u << ((c & 3) * 8));   // ds_add, no return
        }
        __syncthreads();
        unsigned int* dst = hist8 + (size_t)g * NW + w0;
        for (int w = threadIdx.x; w < nw; w += 256) dst[w] = h[w];
        return;
    }

    // ---- gemm block ----
    const int t = threadIdx.x;
    const int w = t >> 6, lane = t & 63;
    const int row0 = (int)blockIdx.x * BM;
    const int m = lane & 15, q = lane >> 4;

    // LDS row r: quad Lq holds global quad Lq ^ (r&7) (bank-conflict-free b128 reads);
    // gload_lds writes linearly -> inverse swizzle folded into global source address.
    auto stage = [&](int buf, int c0) {
#pragma unroll
        for (int j = 0; j < 4; ++j) {
            int i = w * 4 + j;
            int r = i * 4 + (lane >> 4);
            int rg = row0 + r; rg = rg < N ? rg : N - 1;   // tail clamp (dup reads, discarded)
            int k = ((lane & 15) ^ (r & 7)) << 2;
            const float* src = x + (size_t)rg * IN_CH + c0 * BK + k;
            __builtin_amdgcn_global_load_lds(
                (const __attribute__((address_space(1))) void*)src,
                (__attribute__((address_space(3))) void*)&xs[buf][i * 256], 16, 0, 0);
        }
    };

    const unsigned short* wr = Wt + (size_t)m * IN_CH + q * 8;
    const int pm = m & 7;
    const int rowbase = (w * 16 + m) * BK;
    f32x4 acc[4];
#pragma unroll
    for (int tt = 0; tt < 4; ++tt) acc[tt] = (f32x4){0.f, 0.f, 0.f, 0.f};

    stage(0, 0);
    int cur = 0;
    for (int c0 = 0; c0 < IN_CH / BK; ++c0) {   // 8 chunks
        __syncthreads();                         // buffer 'cur' ready; prev reads done
        if (c0 < IN_CH / BK - 1) stage(cur ^ 1, c0 + 1);   // async prefetch overlaps compute
#pragma unroll
        for (int s = 0; s < 2; ++s) {            // two K=32 MFMA steps per chunk
            int qi = s * 8 + q * 2;
            f32x4 a0 = *(const f32x4*)&xs[cur][rowbase + (((qi    ) ^ pm) << 2)];
            f32x4 a1 = *(const f32x4*)&xs[cur][rowbase + (((qi + 1) ^ pm) << 2)];
            short8 af;
            af[0] = (short)bf16bits(a0[0]); af[1] = (short)bf16bits(a0[1]);
            af[2] = (short)bf16bits(a0[2]); af[3] = (short)bf16bits(a0[3]);
            af[4] = (short)bf16bits(a1[0]); af[5] = (short)bf16bits(a1[1]);
            af[6] = (short)bf16bits(a1[2]); af[7] = (short)bf16bits(a1[3]);
#pragma unroll
            for (int tt = 0; tt < 4; ++tt) {
                short8 bf = *(const short8*)(wr + (size_t)tt * 16 * IN_CH + c0 * BK + s * 32);
                acc[tt] = __builtin_amdgcn_mfma_f32_16x16x32_bf16(af, bf, acc[tt], 0, 0, 0);
            }
        }
        cur ^= 1;
    }
    // C/D layout: col = lane&15, row (within 16) = q*4 + reg
    int rbase = row0 + w * 16 + q * 4;
#pragma unroll
    for (int r = 0; r < 4; ++r) {
        int row = rbase + r;
        if (row < N) {
#pragma unroll
            for (int tt = 0; tt < 4; ++tt)
                hs[(size_t)row * OUT_CH + tt * 16 + m] = bf16bits(acc[tt][r]);
        }
    }
}

// --- reduce: block = 64 words x all 256 planes. Wave wv holds its 64 plane-values in
//     registers (static idx), coalesced rows both ways; cross-wave prefix via LDS. ---
__global__ void __launch_bounds__(256) reduce_kernel(const unsigned int* __restrict__ hist8,
                                                     unsigned int* __restrict__ pre8,
                                                     unsigned int* __restrict__ cnt,
                                                     int N, int NW) {
    __shared__ unsigned int wsum[4][64];
    int lane = threadIdx.x & 63, wv = threadIdx.x >> 6;
    int w = (int)blockIdx.x * 64 + lane;
    bool act = w < NW;
    const unsigned int* hp = hist8 + (size_t)wv * 64 * NW + w;
    unsigned int v[64];
#pragma unroll
    for (int j = 0; j < 64; ++j) v[j] = act ? hp[(size_t)j * NW] : 0u;
    unsigned int s = 0;
#pragma unroll
    for (int j = 0; j < 64; ++j) s += v[j];
    wsum[wv][lane] = s;
    __syncthreads();
    unsigned int run = 0;
    for (int k = 0; k < wv; ++k) run += wsum[k][lane];
    if (act) {
        unsigned int* pp = pre8 + (size_t)wv * 64 * NW + w;
#pragma unroll
        for (int j = 0; j < 64; ++j) { pp[(size_t)j * NW] = run; run += v[j]; }
        if (wv == 3) {   // run = total over all 256 planes (packed bytes, carry-free)
            int n0 = w * 4;
            if (n0 + 3 < N) {
                uint4 cv = {run & 0xffu, (run >> 8) & 0xffu, (run >> 16) & 0xffu, (run >> 24) & 0xffu};
                *(uint4*)&cnt[n0] = cv;
            } else {
                for (int j = 0; j < 4 && n0 + j < N; ++j) cnt[n0 + j] = (run >> (j * 8)) & 0xffu;
            }
        }
    }
}

// --- scan A: exclusive scan of padded counts; packs cnt into rowptr top byte; also dinv ---
__global__ void scan_a(const unsigned int* __restrict__ cnt, float* __restrict__ dinv,
                       unsigned int* __restrict__ rowptr, unsigned int* __restrict__ blockSums, int N) {
    __shared__ unsigned int wsum[4];
    int t = threadIdx.x, b = blockIdx.x;
    int base = b * SCAN_CHUNK + t * 8;
    unsigned int p[8], vv[8];
    unsigned int run = 0;
#pragma unroll
    for (int j = 0; j < 8; ++j) {
        unsigned int v = (base + j < N) ? cnt[base + j] : 0u;
        if (base + j < N) dinv[base + j] = rsqrtf((float)(v + 1u));
        vv[j] = v;
        p[j] = run;
        run += (v + 3u) & ~3u;   // pad to mult of 4 -> segment starts uint4-aligned
    }
    unsigned int s = run;
    unsigned int si = s;
#pragma unroll
    for (int off = 1; off < 64; off <<= 1) {
        unsigned int o = __shfl_up(si, off, 64);
        if ((t & 63) >= off) si += o;
    }
    if ((t & 63) == 63) wsum[t >> 6] = si;
    __syncthreads();
    unsigned int woff = 0;
    int w = t >> 6;
    for (int k = 0; k < w; ++k) woff += wsum[k];
    unsigned int exc = woff + si - s;
#pragma unroll
    for (int j = 0; j < 8; ++j)
        if (base + j < N) rowptr[base + j] = (exc + p[j]) | (vv[j] << 24);   // pack cnt in top byte
    if (t == 255) blockSums[b] = woff + si;
}

// --- scan B: exclusive scan of block totals (single wave, nb<=64) ---
__global__ void scan_b(const unsigned int* __restrict__ blockSums, unsigned int* __restrict__ blockOff, int nb) {
    int t = threadIdx.x;
    unsigned int s = (t < nb) ? blockSums[t] : 0u;
    unsigned int si = s;
#pragma unroll
    for (int off = 1; off < 64; off <<= 1) {
        unsigned int o = __shfl_up(si, off, 64);
        if (t >= off) si += o;
    }
    blockOff[t] = si - s;
}

// --- fill: (partition, quadrant) blocks; LDS cursors preloaded with pre8 plane slice;
//     atomicAdd returns base+rank directly. 25KB LDS -> ~6 blocks/CU (was 1). ---
__global__ void __launch_bounds__(256, 8) fill_kernel(const int* __restrict__ ei,
                                                      const unsigned int* __restrict__ rowptr,
                                                      const unsigned int* __restrict__ blockOff,
                                                      const unsigned int* __restrict__ pre8,
                                                      unsigned int* __restrict__ srcIdx,
                                                      int N, int E) {
    __shared__ unsigned int cur[NWQ_MAX];
    int NW = (N + 3) >> 2;
    int NWQ = (NW + NQUAD - 1) / NQUAD;
    int b = blockIdx.x;
    int g = b >> 2, quad = b & 3;
    int w0 = quad * NWQ, w1 = min(w0 + NWQ, NW);
    int nw = w1 - w0;
    const unsigned int* pre = pre8 + (size_t)g * NW + w0;
    for (int w = threadIdx.x; w < nw; w += 256) cur[w] = pre[w];
    __syncthreads();
    int P = (E + G_PART - 1) / G_PART;
    int e0 = g * P, e1 = min(e0 + P, E);
    for (int e = e0 + (int)threadIdx.x; e < e1; e += 256) {
        int c = ei[E + e];    // target
        int wq = c >> 2;
        if (wq >= w0 && wq < w1) {
            int r = ei[e];    // source
            int sh = (c & 3) * 8;
            unsigned int old = atomicAdd(&cur[wq - w0], 1u << sh);
            unsigned int pos = (rowptr[c] & 0xffffffu) + blockOff[c >> 11] + ((old >> sh) & 0xffu);
            srcIdx[pos] = (unsigned int)r;
        }
    }
}

// --- fused gather + self + bias + log_softmax. One wave/node; half-waves cover 4 edges each.
//     rowptr packs {cnt:8, offset:24}. hs UNSCALED; tail slots clamp to sentinel N. ---
__global__ void __launch_bounds__(256) gather_kernel(const unsigned int* __restrict__ srcIdx,
                                                     const unsigned int* __restrict__ rowptr,
                                                     const unsigned int* __restrict__ blockOff,
                                                     const float* __restrict__ dinv,
                                                     const unsigned short* __restrict__ hs,
                                                     const float* __restrict__ bias,
                                                     float* __restrict__ out, int N) {
    int node = (int)((blockIdx.x * (unsigned long long)blockDim.x + threadIdx.x) >> 6);
    int lane = threadIdx.x & 63;
    if (node >= N) return;
    int sub = lane >> 5, ch2 = lane & 31;   // lane covers channels 2*ch2, 2*ch2+1
    unsigned int rp = rowptr[node];
    unsigned int start = (rp & 0xffffffu) + blockOff[node >> 11];
    unsigned int cn = rp >> 24;
    unsigned int iters = (cn + 7u) >> 3;   // 8 edges per iter (4 per half-wave)
    const uint4* sp = (const uint4*)(srcIdx + start + sub * 4);
    unsigned int sent = (unsigned int)N;
    float acc0 = 0.f, acc1 = 0.f;
    for (unsigned int it = 0; it < iters; ++it) {
        uint4 iv = sp[it * 2];
        unsigned int slot = it * 8u + (unsigned int)sub * 4u;
        unsigned int i0 = (slot + 0u < cn) ? iv.x : sent;
        unsigned int i1 = (slot + 1u < cn) ? iv.y : sent;
        unsigned int i2 = (slot + 2u < cn) ? iv.z : sent;
        unsigned int i3 = (slot + 3u < cn) ? iv.w : sent;
        float d0 = dinv[i0], d1 = dinv[i1], d2 = dinv[i2], d3 = dinv[i3];
        unsigned int u0 = *(const unsigned int*)(hs + (size_t)i0 * OUT_CH + 2 * ch2);
        unsigned int u1 = *(const unsigned int*)(hs + (size_t)i1 * OUT_CH + 2 * ch2);
        unsigned int u2 = *(const unsigned int*)(hs + (size_t)i2 * OUT_CH + 2 * ch2);
        unsigned int u3 = *(const unsigned int*)(hs + (size_t)i3 * OUT_CH + 2 * ch2);
        acc0 += bflo(u0) * d0 + bflo(u1) * d1 + bflo(u2) * d2 + bflo(u3) * d3;
        acc1 += bfhi(u0) * d0 + bfhi(u1) * d1 + bfhi(u2) * d2 + bfhi(u3) * d3;
    }
    acc0 += __shfl_xor(acc0, 32, 64);
    acc1 += __shfl_xor(acc1, 32, 64);
    float di = dinv[node];
    unsigned int us = *(const unsigned int*)(hs + (size_t)node * OUT_CH + 2 * ch2);
    acc0 = fmaf(bflo(us), di, acc0);
    acc1 = fmaf(bfhi(us), di, acc1);
    float2 bb = *(const float2*)(bias + 2 * ch2);
    float v0 = fmaf(acc0, di, bb.x);
    float v1 = fmaf(acc1, di, bb.y);
    float mx = fmaxf(v0, v1);
#pragma unroll
    for (int off = 16; off > 0; off >>= 1) mx = fmaxf(mx, __shfl_xor(mx, off, 64));
    float s = expf(v0 - mx) + expf(v1 - mx);
#pragma unroll
    for (int off = 16; off > 0; off >>= 1) s += __shfl_xor(s, off, 64);
    float ls = logf(s);
    if (sub == 0) {
        float2 o = {v0 - mx - ls, v1 - mx - ls};
        *(float2*)(out + (size_t)node * OUT_CH + 2 * ch2) = o;
    }
}

extern "C" void kernel_launch(void* const* d_in, const int* in_sizes, int n_in,
                              void* d_out, int out_size, void* d_ws, size_t ws_size,
                              hipStream_t stream) {
    const float* x  = (const float*)d_in[0];
    const int*   ei = (const int*)d_in[1];
    const float* W  = (const float*)d_in[2];
    const float* b  = (const float*)d_in[3];
    float* out = (float*)d_out;

    const int N = in_sizes[0] / IN_CH;   // 100000
    const int E = in_sizes[1] / 2;       // 1600000
    const int NBLK = (N + SCAN_CHUNK - 1) / SCAN_CHUNK;  // 49
    const int NW = (N + 3) / 4;          // 25000 packed histogram words

    char* ws = (char*)d_ws;
    size_t o = 0;
    unsigned int* cnt      = (unsigned int*)(ws + o); o += (size_t)N * 4;
    unsigned int* rowptr   = (unsigned int*)(ws + o); o += (size_t)N * 4;
    unsigned int* blockSums= (unsigned int*)(ws + o); o += 256;
    unsigned int* blockOff = (unsigned int*)(ws + o); o += 256;
    float*        dinv     = (float*)(ws + o);        o += ((size_t)(N + 1) * 4 + 15) & ~15ull;
    // hist8 (G_PART planes of NW words) aliases srcIdx: hist8 dead after reduce_kernel,
    // srcIdx written only in fill_kernel (after reduce). Region = max of the two.
    size_t histBytes   = (size_t)G_PART * NW * 4;
    size_t srcIdxBytes = ((size_t)E + 3u * (size_t)N + 64) * 4;
    unsigned int* hist8    = (unsigned int*)(ws + o);
    unsigned int* srcIdx   = (unsigned int*)(ws + o); o += (histBytes > srcIdxBytes ? histBytes : srcIdxBytes);
    unsigned int* pre8     = (unsigned int*)(ws + o); o += histBytes;
    unsigned short* Wt     = (unsigned short*)(ws + o); o += (size_t)IN_CH * OUT_CH * 2;
    unsigned short* hs     = (unsigned short*)(ws + o); o += (size_t)(N + 1) * OUT_CH * 2;

    const int GB = (N + BM - 1) / BM;             // gemm blocks = 1563
    const int HB = G_PART * NQUAD;                // histo/fill blocks = 1024

    prep_kernel<<<129, 256, 0, stream>>>(W, Wt, hs, dinv, N);
    gemm_histo<<<GB + HB, 256, 0, stream>>>(x, Wt, hs, N, ei + E, hist8, E, GB);
    reduce_kernel<<<(NW + 63) / 64, 256, 0, stream>>>(hist8, pre8, cnt, N, NW);
    scan_a<<<NBLK, 256, 0, stream>>>(cnt, dinv, rowptr, blockSums, N);
    scan_b<<<1, 64, 0, stream>>>(blockSums, blockOff, NBLK);
    fill_kernel<<<HB, 256, 0, stream>>>(ei, rowptr, blockOff, pre8, srcIdx, N, E);
    gather_kernel<<<((size_t)N * 64 + 255) / 256, 256, 0, stream>>>(srcIdx, rowptr, blockOff, dinv, hs, b, out, N);
}